// Round 5
// baseline (170.787 us; speedup 1.0000x reference)
//
#include <hip/hip_runtime.h>

// B=2, N=64, D=256, H=8, DK=32.  ROWS = B*N*N = 8192.
#define ROWS 8192
#define DIM  256

typedef short short8 __attribute__((ext_vector_type(8)));
typedef float f4     __attribute__((ext_vector_type(4)));

__device__ __forceinline__ float bf2f(unsigned int u16) {
    union { unsigned int i; float f; } v;
    v.i = (u16 & 0xffffu) << 16;
    return v.f;
}
__device__ __forceinline__ unsigned short f2bf(float f) {
    union { float f; unsigned int u; } v; v.f = f;
    unsigned int r = v.u + 0x7fffu + ((v.u >> 16) & 1u);   // RNE
    return (unsigned short)(r >> 16);
}

// ---------------------------------------------------------------------------
// Merged casts. Blocks [0,2048): x(8192x256 fp32)->xb bf16.
// Blocks [2048,2624): weights -> WT[n][k] bf16 packed.
//   w0..w4 at w*65536 ; W1(256x512)->512x256 @327680 ; W2(512x256)->256x512 @458752
// ---------------------------------------------------------------------------
__global__ __launch_bounds__(256)
void cast_all(const float* __restrict__ x, unsigned short* __restrict__ xb,
              const float* __restrict__ w0, const float* __restrict__ w1,
              const float* __restrict__ w2, const float* __restrict__ w3,
              const float* __restrict__ w4, const float* __restrict__ w5,
              const float* __restrict__ w6, unsigned short* __restrict__ wt)
{
    if (blockIdx.x < 2048) {
        const size_t i = ((size_t)blockIdx.x * 256 + threadIdx.x) * 4;
        float4 v = *(const float4*)(x + i);
        uint2 p;
        p.x = f2bf(v.x) | ((unsigned int)f2bf(v.y) << 16);
        p.y = f2bf(v.z) | ((unsigned int)f2bf(v.w) << 16);
        *(uint2*)(xb + i) = p;
        return;
    }
    __shared__ float t[32][33];
    int id = blockIdx.x - 2048;
    const float* src; int K, N, Ntiles; size_t doff;
    if (id < 320) {
        int w = id >> 6; id &= 63; K = 256; N = 256; Ntiles = 8;
        doff = (size_t)w * 65536;
        src = (w == 0) ? w0 : (w == 1) ? w1 : (w == 2) ? w2 : (w == 3) ? w3 : w4;
    } else if (id < 448) {
        id -= 320; K = 256; N = 512; Ntiles = 16; doff = 327680; src = w5;
    } else {
        id -= 448; K = 512; N = 256; Ntiles = 8;  doff = 458752; src = w6;
    }
    const int tk = id / Ntiles, tn = id % Ntiles;
    const int k0 = tk * 32, n0 = tn * 32;
    const int c = threadIdx.x & 31, r8 = threadIdx.x >> 5;
    for (int rr = r8; rr < 32; rr += 8)
        t[rr][c] = src[(size_t)(k0 + rr) * N + n0 + c];
    __syncthreads();
    for (int rr = r8; rr < 32; rr += 8)
        wt[doff + (size_t)(n0 + rr) * K + k0 + c] = f2bf(t[c][rr]);
}

// ---------------------------------------------------------------------------
// Projection MFMA GEMM with head-major scatter epilogue.
//   wsel 0 (lk): dst[b][h][x=i][a=j][d]   wsel 1 (rk): dst[b][h][a=i][y=j][d]
//   wsel 2 (lv): dst[b][h][x=i][a=j][d]   wsel 3 (rv): dst[b][h][y=j][a=i][d]
// grid = (16, 64)
// ---------------------------------------------------------------------------
__global__ __launch_bounds__(256)
void proj_mfma(const unsigned short* __restrict__ A, const unsigned short* __restrict__ WT,
               unsigned short* __restrict__ projT)
{
    const int lane = threadIdx.x & 63, wave = threadIdx.x >> 6;
    const int wsel = blockIdx.x >> 2;
    const int col0 = (blockIdx.x & 3) * 64;
    const int m0 = blockIdx.y * 128 + wave * 32;
    const int lm = lane & 15, lk8 = (lane >> 4) * 8;
    const unsigned short* W = WT + (size_t)wsel * 65536;
    unsigned short* dst = projT + (size_t)wsel * 2097152;

    f4 acc[2][4];
    #pragma unroll
    for (int i = 0; i < 2; ++i)
        #pragma unroll
        for (int j = 0; j < 4; ++j) acc[i][j] = (f4){0.f, 0.f, 0.f, 0.f};

    #pragma unroll 2
    for (int kc = 0; kc < 256; kc += 32) {
        short8 af[2], bf[4];
        #pragma unroll
        for (int i = 0; i < 2; ++i)
            af[i] = *(const short8*)(A + (size_t)(m0 + i * 16 + lm) * 256 + kc + lk8);
        #pragma unroll
        for (int j = 0; j < 4; ++j)
            bf[j] = *(const short8*)(W + (size_t)(col0 + j * 16 + lm) * 256 + kc + lk8);
        #pragma unroll
        for (int i = 0; i < 2; ++i)
            #pragma unroll
            for (int j = 0; j < 4; ++j)
                acc[i][j] = __builtin_amdgcn_mfma_f32_16x16x32_bf16(af[i], bf[j], acc[i][j], 0, 0, 0);
    }

    const int rbase = (lane >> 4) * 4;
    const int swap = (wsel == 3);
    #pragma unroll
    for (int i = 0; i < 2; ++i)
        #pragma unroll
        for (int j = 0; j < 4; ++j) {
            const int c = col0 + j * 16 + lm;
            const int h = c >> 5, d = c & 31;
            #pragma unroll
            for (int r = 0; r < 4; ++r) {
                const int m = m0 + i * 16 + rbase + r;
                const int b = m >> 12, ii = (m >> 6) & 63, jj = m & 63;
                const int p = swap ? jj : ii;
                const int q = swap ? ii : jj;
                const size_t idx = ((((size_t)b * 8 + h) * 64 + p) * 64 + q) * 32 + d;
                dst[idx] = f2bf(acc[i][j][r]);
            }
        }
}

// ---------------------------------------------------------------------------
// Scores via MFMA: per (b,h), wave w handles a = a0 + w.
//   S_a[x,y] = sum_d lk[x,a,d]*rk[a,y,d] / sqrt(32), stored bf16 as
//   S[b][h][x][a][y].  grid = 256 (b,h,a/4), 256 thr.
// ---------------------------------------------------------------------------
__global__ __launch_bounds__(256)
void scores_mfma(const unsigned short* __restrict__ lkT, const unsigned short* __restrict__ rkT,
                 unsigned short* __restrict__ S)
{
    const int lane = threadIdx.x & 63, wave = threadIdx.x >> 6;
    const int bi = blockIdx.x;
    const int b = bi >> 7, h = (bi >> 4) & 7, a = (bi & 15) * 4 + wave;
    const size_t bh = (size_t)b * 8 + h;
    const int lm = lane & 15, lk8 = (lane >> 4) * 8;

    short8 af[4], bf[4];
    #pragma unroll
    for (int t = 0; t < 4; ++t) {
        af[t] = *(const short8*)(lkT + ((bh * 64 + (t * 16 + lm)) * 64 + a) * 32 + lk8);
        bf[t] = *(const short8*)(rkT + ((bh * 64 + a) * 64 + (t * 16 + lm)) * 32 + lk8);
    }
    const int rbase = (lane >> 4) * 4;
    unsigned short* Sb = S + bh * 262144 + a * 64;   // + x*4096 + y
    #pragma unroll
    for (int mt = 0; mt < 4; ++mt)
        #pragma unroll
        for (int nt = 0; nt < 4; ++nt) {
            f4 acc = (f4){0.f, 0.f, 0.f, 0.f};
            acc = __builtin_amdgcn_mfma_f32_16x16x32_bf16(af[mt], bf[nt], acc, 0, 0, 0);
            #pragma unroll
            for (int r = 0; r < 4; ++r) {
                const int xx = mt * 16 + rbase + r;
                const int yy = nt * 16 + lm;
                Sb[(size_t)xx * 4096 + yy] = f2bf(acc[r] * 0.17677669529663687f);
            }
        }
}

// ---------------------------------------------------------------------------
// Softmax over a + aggregation, block per (b, h, x-quad), 512 thr, grid 256.
// R4 model: effective L2 read rate is ~11 B/cy/CU (per-CU miss cap), so the
// old per-x blocks re-reading the full 256KB rvT[bh] panel (268 MB total)
// made this a ~43us kernel hiding just under the 41us harness fills.
// 4 x per block: each rv line loaded once feeds 4 x-accumulators in regs ->
// rv traffic 268 -> 67 MB.  LDS ~103KB (att f32 + lv f32), 1 block/CU.
// obuf[(b*64+x)*64+y][h*32+d] bf16.
// ---------------------------------------------------------------------------
__global__ __launch_bounds__(512)
void softmax_agg(const unsigned short* __restrict__ S, const unsigned short* __restrict__ lvT,
                 const unsigned short* __restrict__ rvT, unsigned short* __restrict__ obuf)
{
    __shared__ float att[4][64][64];        // [x][a][y]  64KB
    __shared__ float lvL[4][64][32];        // 32KB
    __shared__ float smx[4][2][64], ssm[4][2][64], invL[4][64];
    const int bi = blockIdx.x;              // b(1b) h(3b) xq(4b)
    const int b = bi >> 7, h = (bi >> 4) & 7, xq = bi & 15;
    const int x0 = xq * 4;
    const size_t bh = (size_t)b * 8 + h;
    const int tid = threadIdx.x;

    {   // stage S (4 x 8KB bf16) -> att f32 ; lv (4 x 4KB) -> f32
        const int xi = tid >> 7;            // 0..3
        const int t2 = tid & 127;
        const int a = t2 >> 1;
        const int yo = (t2 & 1) * 32;
        const unsigned short* Sp = S + (bh * 64 + (x0 + xi)) * 4096 + a * 64 + yo;
        #pragma unroll
        for (int u = 0; u < 4; ++u) {
            uint4 p = *(const uint4*)(Sp + u * 8);
            float* d = &att[xi][a][yo + u * 8];
            d[0] = bf2f(p.x); d[1] = bf2f(p.x >> 16);
            d[2] = bf2f(p.y); d[3] = bf2f(p.y >> 16);
            d[4] = bf2f(p.z); d[5] = bf2f(p.z >> 16);
            d[6] = bf2f(p.w); d[7] = bf2f(p.w >> 16);
        }
        const int d0 = (t2 & 1) * 16;
        const unsigned short* Lp = lvT + ((bh * 64 + (x0 + xi)) * 64 + a) * 32 + d0;
        #pragma unroll
        for (int u = 0; u < 2; ++u) {
            uint4 q = *(const uint4*)(Lp + u * 8);
            float* d = &lvL[xi][a][d0 + u * 8];
            d[0] = bf2f(q.x); d[1] = bf2f(q.x >> 16);
            d[2] = bf2f(q.y); d[3] = bf2f(q.y >> 16);
            d[4] = bf2f(q.z); d[5] = bf2f(q.z >> 16);
            d[6] = bf2f(q.w); d[7] = bf2f(q.w >> 16);
        }
    }
    __syncthreads();

    {   // per-(x,y) max over a, 2-way split
        const int xi = tid >> 7, az = (tid >> 6) & 1, y = tid & 63;
        float mx = -1e30f;
        for (int a = az; a < 64; a += 2) mx = fmaxf(mx, att[xi][a][y]);
        smx[xi][az][y] = mx;
    }
    __syncthreads();

    {   // exp + partial sums
        const int xi = tid >> 7, az = (tid >> 6) & 1, y = tid & 63;
        const float mx = fmaxf(smx[xi][0][y], smx[xi][1][y]);
        float s = 0.f;
        for (int a = az; a < 64; a += 2) {
            float e = __expf(att[xi][a][y] - mx);
            att[xi][a][y] = e;
            s += e;
        }
        ssm[xi][az][y] = s;
    }
    __syncthreads();
    if (tid < 256) {
        const int xi = tid >> 6, y = tid & 63;
        invL[xi][y] = 1.f / (ssm[xi][0][y] + ssm[xi][1][y]);
    }
    __syncthreads();

    {   // aggregation; thread = (dp, yb); y = yb + 32*it; rv line reused 4x
        const int dp = tid & 15, yb = tid >> 4;   // yb 0..31
        #pragma unroll
        for (int it = 0; it < 2; ++it) {
            const int y = yb + it * 32;
            const unsigned short* rvr = rvT + (bh * 64 + y) * 2048 + dp * 2;
            float a0[4] = {0.f, 0.f, 0.f, 0.f}, a1[4] = {0.f, 0.f, 0.f, 0.f};
            #pragma unroll 4
            for (int a = 0; a < 64; ++a) {
                unsigned int pk = *(const unsigned int*)(rvr + a * 32);
                const float lo = bf2f(pk), hi = bf2f(pk >> 16);
                #pragma unroll
                for (int xi = 0; xi < 4; ++xi) {
                    const float w = att[xi][a][y];
                    const float2 lv2 = *(const float2*)&lvL[xi][a][2 * dp];
                    a0[xi] = fmaf(w * lv2.x, lo, a0[xi]);
                    a1[xi] = fmaf(w * lv2.y, hi, a1[xi]);
                }
            }
            #pragma unroll
            for (int xi = 0; xi < 4; ++xi) {
                const float inv = invL[xi][y];
                unsigned int st = f2bf(a0[xi] * inv) | ((unsigned int)f2bf(a1[xi] * inv) << 16);
                *(unsigned int*)(obuf + (((size_t)b * 64 + (x0 + xi)) * 64 + y) * 256 + h * 32 + dp * 2) = st;
            }
        }
    }
}

// ---------------------------------------------------------------------------
// XOR swizzle on 16B chunks: row stride of both LDS tiles is a multiple of
// 128B, so unswizzled column reads (16 lanes, same col, rows 0..15) would be
// a 16-way bank conflict. chunk' = chunk ^ (row & 7) spreads them over 8
// chunk slots (2-way = free, m136).
// ---------------------------------------------------------------------------
__device__ __forceinline__ int swz8(int r, int c, int rl) {
    return r * rl + ((((c >> 3) ^ (r & 7)) << 3) | (c & 7));
}

// ---------------------------------------------------------------------------
// Fused FFN tail: one block per 32 output rows, 512 thr / 8 waves (grid 256).
//   phase 1: h   = LN(x + obuf @ WoT^T)   wave w: cols w*32..+31, rows 0..31
//   phase 2: mid = relu(h @ W1T^T + b1)   wave w: cols w*64..+63, rows 0..31
//   phase 3: out = LN(h + mid @ W2T^T+b2) wave w: cols w*32..+31, rows 0..31
// R2/R3 post-mortem: ILP (VGPR cap lift) and TLP (2x waves) both no-ops ->
// bottleneck is per-CU line-transaction / hot-line L2 throughput on the
// weight stream (every block re-reads all 640KB of weights). BM 16->32
// halves total weight traffic (320->160MB) and per-CU transactions.
// ---------------------------------------------------------------------------
__global__ __launch_bounds__(512, 2)
void ffn_fused(const unsigned short* __restrict__ A,
               const unsigned short* __restrict__ WoT,
               const unsigned short* __restrict__ W1T,
               const unsigned short* __restrict__ W2T,
               const float* __restrict__ xres,
               const float* __restrict__ g1, const float* __restrict__ be1,
               const float* __restrict__ b1, const float* __restrict__ b2,
               const float* __restrict__ g2, const float* __restrict__ be2,
               float* __restrict__ out)
{
    __shared__ unsigned short hs[32 * 256];   // h   32x256 bf16, swizzled (16KB)
    __shared__ unsigned short ms[32 * 512];   // mid 32x512 bf16, swizzled (32KB)
    __shared__ float ps[32][8], pq[32][8];
    const int lane = threadIdx.x & 63, wave = threadIdx.x >> 6;
    const int m0 = blockIdx.x * 32;
    const int lm = lane & 15, lk8 = (lane >> 4) * 8;
    const int rbase = (lane >> 4) * 4;
    const int col0 = wave * 32;               // phases 1/3: 32 cols per wave
    float hreg[2][2][4];                      // [row-tile][col-tile][r]

    // ---------- phase 1: h = LN(x + A @ WoT^T) ----------
    {
        f4 acc[2][2];
        #pragma unroll
        for (int i = 0; i < 2; ++i)
            #pragma unroll
            for (int j = 0; j < 2; ++j) acc[i][j] = (f4){0.f, 0.f, 0.f, 0.f};
        #pragma unroll
        for (int kc = 0; kc < 256; kc += 32) {
            short8 af[2], bf[2];
            #pragma unroll
            for (int i = 0; i < 2; ++i)
                af[i] = *(const short8*)(A + (size_t)(m0 + i * 16 + lm) * 256 + kc + lk8);
            #pragma unroll
            for (int j = 0; j < 2; ++j)
                bf[j] = *(const short8*)(WoT + (size_t)(col0 + j * 16 + lm) * 256 + kc + lk8);
            #pragma unroll
            for (int i = 0; i < 2; ++i)
                #pragma unroll
                for (int j = 0; j < 2; ++j)
                    acc[i][j] = __builtin_amdgcn_mfma_f32_16x16x32_bf16(af[i], bf[j], acc[i][j], 0, 0, 0);
        }
        float v[2][2][4], s[2][4], q[2][4];
        #pragma unroll
        for (int i = 0; i < 2; ++i)
            #pragma unroll
            for (int r = 0; r < 4; ++r) { s[i][r] = 0.f; q[i][r] = 0.f; }
        #pragma unroll
        for (int i = 0; i < 2; ++i)
            #pragma unroll
            for (int j = 0; j < 2; ++j) {
                const int n = col0 + j * 16 + lm;
                #pragma unroll
                for (int r = 0; r < 4; ++r) {
                    const float t = acc[i][j][r] + xres[(size_t)(m0 + i * 16 + rbase + r) * 256 + n];
                    v[i][j][r] = t;
                    s[i][r] += t;
                    q[i][r] = fmaf(t, t, q[i][r]);
                }
            }
        #pragma unroll
        for (int off = 1; off < 16; off <<= 1)
            #pragma unroll
            for (int i = 0; i < 2; ++i)
                #pragma unroll
                for (int r = 0; r < 4; ++r) {
                    s[i][r] += __shfl_xor(s[i][r], off);
                    q[i][r] += __shfl_xor(q[i][r], off);
                }
        if (lm == 0)
            #pragma unroll
            for (int i = 0; i < 2; ++i)
                #pragma unroll
                for (int r = 0; r < 4; ++r) {
                    ps[i * 16 + rbase + r][wave] = s[i][r];
                    pq[i * 16 + rbase + r][wave] = q[i][r];
                }
        __syncthreads();
        #pragma unroll
        for (int i = 0; i < 2; ++i)
            #pragma unroll
            for (int r = 0; r < 4; ++r) {
                const int lr = i * 16 + rbase + r;
                const float Sm = ps[lr][0] + ps[lr][1] + ps[lr][2] + ps[lr][3]
                               + ps[lr][4] + ps[lr][5] + ps[lr][6] + ps[lr][7];
                const float Qm = pq[lr][0] + pq[lr][1] + pq[lr][2] + pq[lr][3]
                               + pq[lr][4] + pq[lr][5] + pq[lr][6] + pq[lr][7];
                const float mu = Sm * (1.f / 256.f);
                const float ri = rsqrtf(Qm * (1.f / 256.f) - mu * mu + 1e-5f);
                #pragma unroll
                for (int j = 0; j < 2; ++j) {
                    const int n = col0 + j * 16 + lm;
                    const unsigned short hb16 = f2bf((v[i][j][r] - mu) * ri * g1[n] + be1[n]);
                    hs[swz8(lr, n, 256)] = hb16;
                    hreg[i][j][r] = bf2f(hb16);
                }
            }
    }
    __syncthreads();

    // ---------- phase 2: mid = relu(h @ W1T^T + b1) ----------
    {
        const int c0 = wave * 64;
        f4 acc2[2][4];
        #pragma unroll
        for (int i = 0; i < 2; ++i)
            #pragma unroll
            for (int j = 0; j < 4; ++j) acc2[i][j] = (f4){0.f, 0.f, 0.f, 0.f};
        #pragma unroll
        for (int kc = 0; kc < 256; kc += 32) {
            short8 af[2], bf[4];
            #pragma unroll
            for (int i = 0; i < 2; ++i)
                af[i] = *(const short8*)(hs + swz8(i * 16 + lm, kc + lk8, 256));
            #pragma unroll
            for (int j = 0; j < 4; ++j)
                bf[j] = *(const short8*)(W1T + (size_t)(c0 + j * 16 + lm) * 256 + kc + lk8);
            #pragma unroll
            for (int i = 0; i < 2; ++i)
                #pragma unroll
                for (int j = 0; j < 4; ++j)
                    acc2[i][j] = __builtin_amdgcn_mfma_f32_16x16x32_bf16(af[i], bf[j], acc2[i][j], 0, 0, 0);
        }
        #pragma unroll
        for (int i = 0; i < 2; ++i)
            #pragma unroll
            for (int j = 0; j < 4; ++j) {
                const int n = c0 + j * 16 + lm;
                const float bb = b1[n];
                #pragma unroll
                for (int r = 0; r < 4; ++r)
                    ms[swz8(i * 16 + rbase + r, n, 512)] = f2bf(fmaxf(acc2[i][j][r] + bb, 0.f));
            }
    }
    __syncthreads();

    // ---------- phase 3: out = LN(h + mid @ W2T^T + b2) ----------
    {
        f4 acc[2][2];
        #pragma unroll
        for (int i = 0; i < 2; ++i)
            #pragma unroll
            for (int j = 0; j < 2; ++j) acc[i][j] = (f4){0.f, 0.f, 0.f, 0.f};
        #pragma unroll
        for (int kc = 0; kc < 512; kc += 32) {
            short8 af[2], bf[2];
            #pragma unroll
            for (int i = 0; i < 2; ++i)
                af[i] = *(const short8*)(ms + swz8(i * 16 + lm, kc + lk8, 512));
            #pragma unroll
            for (int j = 0; j < 2; ++j)
                bf[j] = *(const short8*)(W2T + (size_t)(col0 + j * 16 + lm) * 512 + kc + lk8);
            #pragma unroll
            for (int i = 0; i < 2; ++i)
                #pragma unroll
                for (int j = 0; j < 2; ++j)
                    acc[i][j] = __builtin_amdgcn_mfma_f32_16x16x32_bf16(af[i], bf[j], acc[i][j], 0, 0, 0);
        }
        float v[2][2][4], s[2][4], q[2][4];
        #pragma unroll
        for (int i = 0; i < 2; ++i)
            #pragma unroll
            for (int r = 0; r < 4; ++r) { s[i][r] = 0.f; q[i][r] = 0.f; }
        #pragma unroll
        for (int i = 0; i < 2; ++i)
            #pragma unroll
            for (int j = 0; j < 2; ++j) {
                const int n = col0 + j * 16 + lm;
                const float bb = b2[n];
                #pragma unroll
                for (int r = 0; r < 4; ++r) {
                    const float t = acc[i][j][r] + bb + hreg[i][j][r];
                    v[i][j][r] = t;
                    s[i][r] += t;
                    q[i][r] = fmaf(t, t, q[i][r]);
                }
            }
        #pragma unroll
        for (int off = 1; off < 16; off <<= 1)
            #pragma unroll
            for (int i = 0; i < 2; ++i)
                #pragma unroll
                for (int r = 0; r < 4; ++r) {
                    s[i][r] += __shfl_xor(s[i][r], off);
                    q[i][r] += __shfl_xor(q[i][r], off);
                }
        if (lm == 0)
            #pragma unroll
            for (int i = 0; i < 2; ++i)
                #pragma unroll
                for (int r = 0; r < 4; ++r) {
                    ps[i * 16 + rbase + r][wave] = s[i][r];
                    pq[i * 16 + rbase + r][wave] = q[i][r];
                }
        __syncthreads();
        #pragma unroll
        for (int i = 0; i < 2; ++i)
            #pragma unroll
            for (int r = 0; r < 4; ++r) {
                const int lr = i * 16 + rbase + r;
                const float Sm = ps[lr][0] + ps[lr][1] + ps[lr][2] + ps[lr][3]
                               + ps[lr][4] + ps[lr][5] + ps[lr][6] + ps[lr][7];
                const float Qm = pq[lr][0] + pq[lr][1] + pq[lr][2] + pq[lr][3]
                               + pq[lr][4] + pq[lr][5] + pq[lr][6] + pq[lr][7];
                const float mu = Sm * (1.f / 256.f);
                const float ri = rsqrtf(Qm * (1.f / 256.f) - mu * mu + 1e-5f);
                const int m = m0 + lr;
                #pragma unroll
                for (int j = 0; j < 2; ++j) {
                    const int n = col0 + j * 16 + lm;
                    out[(size_t)m * 256 + n] = (v[i][j][r] - mu) * ri * g2[n] + be2[n];
                }
            }
    }
}

// ---------------------------------------------------------------------------
extern "C" void kernel_launch(void* const* d_in, const int* in_sizes, int n_in,
                              void* d_out, int out_size, void* d_ws, size_t ws_size,
                              hipStream_t stream)
{
    const float* x    = (const float*)d_in[0];
    const float* Wlk  = (const float*)d_in[1];
    const float* Wrk  = (const float*)d_in[2];
    const float* Wlv  = (const float*)d_in[3];
    const float* Wrv  = (const float*)d_in[4];
    const float* Wout = (const float*)d_in[5];
    const float* g1   = (const float*)d_in[6];
    const float* be1  = (const float*)d_in[7];
    const float* W1   = (const float*)d_in[8];
    const float* b1   = (const float*)d_in[9];
    const float* W2   = (const float*)d_in[10];
    const float* b2   = (const float*)d_in[11];
    const float* g2   = (const float*)d_in[12];
    const float* be2  = (const float*)d_in[13];

    char* base = (char*)d_ws;
    const size_t MB = 1ull << 20;
    unsigned short* xb    = (unsigned short*)(base + 0);        // 4MB; reused as obuf
    unsigned short* obufb = (unsigned short*)(base + 0);
    unsigned short* projT = (unsigned short*)(base + 4 * MB);   // lkT,rkT,lvT,rvT 4x4MB
    unsigned short* lkT   = projT;
    unsigned short* rkT   = projT + 2097152;
    unsigned short* lvT   = projT + 2 * 2097152;
    unsigned short* rvT   = projT + 3 * 2097152;
    unsigned short* Sbuf  = (unsigned short*)(base + 32 * MB);  // 8MB bf16 scores
    unsigned short* WT    = (unsigned short*)(base + 40 * MB);  // 1.2MB

    // 1. casts (x -> bf16, weights -> transposed bf16)
    cast_all<<<2624, 256, 0, stream>>>(x, xb, Wlk, Wrk, Wlv, Wrv, Wout, W1, W2, WT);
    // 2. projections + head-major scatter
    proj_mfma<<<dim3(16, 64), 256, 0, stream>>>(xb, WT, projT);
    // 3. scores via MFMA -> S (bf16)
    scores_mfma<<<256, 256, 0, stream>>>(lkT, rkT, Sbuf);
    // 4. softmax + aggregation -> obuf (bf16), 4 x per block
    softmax_agg<<<256, 512, 0, stream>>>(Sbuf, lvT, rvT, obufb);
    // 5-7 fused: out = LN( h + relu(h@W1+b1)@W2 + b2 ),  h = LN(x + obuf@W_out)
    ffn_fused<<<256, 512, 0, stream>>>(obufb, WT + 262144, WT + 327680, WT + 458752,
                                       x, g1, be1, b1, b2, g2, be2, (float*)d_out);
}

// Round 6
// 155.805 us; speedup vs baseline: 1.0962x; 1.0962x over previous
//
#include <hip/hip_runtime.h>

// B=2, N=64, D=256, H=8, DK=32.  ROWS = B*N*N = 8192.
#define ROWS 8192
#define DIM  256

typedef short short8 __attribute__((ext_vector_type(8)));
typedef float f4     __attribute__((ext_vector_type(4)));

__device__ __forceinline__ float bf2f(unsigned int u16) {
    union { unsigned int i; float f; } v;
    v.i = (u16 & 0xffffu) << 16;
    return v.f;
}
__device__ __forceinline__ unsigned short f2bf(float f) {
    union { float f; unsigned int u; } v; v.f = f;
    unsigned int r = v.u + 0x7fffu + ((v.u >> 16) & 1u);   // RNE
    return (unsigned short)(r >> 16);
}

// ---------------------------------------------------------------------------
// Merged casts. Blocks [0,2048): x(8192x256 fp32)->xb bf16.
// Blocks [2048,2624): weights -> WT[n][k] bf16 packed.
//   w0..w4 at w*65536 ; W1(256x512)->512x256 @327680 ; W2(512x256)->256x512 @458752
// ---------------------------------------------------------------------------
__global__ __launch_bounds__(256)
void cast_all(const float* __restrict__ x, unsigned short* __restrict__ xb,
              const float* __restrict__ w0, const float* __restrict__ w1,
              const float* __restrict__ w2, const float* __restrict__ w3,
              const float* __restrict__ w4, const float* __restrict__ w5,
              const float* __restrict__ w6, unsigned short* __restrict__ wt)
{
    if (blockIdx.x < 2048) {
        const size_t i = ((size_t)blockIdx.x * 256 + threadIdx.x) * 4;
        float4 v = *(const float4*)(x + i);
        uint2 p;
        p.x = f2bf(v.x) | ((unsigned int)f2bf(v.y) << 16);
        p.y = f2bf(v.z) | ((unsigned int)f2bf(v.w) << 16);
        *(uint2*)(xb + i) = p;
        return;
    }
    __shared__ float t[32][33];
    int id = blockIdx.x - 2048;
    const float* src; int K, N, Ntiles; size_t doff;
    if (id < 320) {
        int w = id >> 6; id &= 63; K = 256; N = 256; Ntiles = 8;
        doff = (size_t)w * 65536;
        src = (w == 0) ? w0 : (w == 1) ? w1 : (w == 2) ? w2 : (w == 3) ? w3 : w4;
    } else if (id < 448) {
        id -= 320; K = 256; N = 512; Ntiles = 16; doff = 327680; src = w5;
    } else {
        id -= 448; K = 512; N = 256; Ntiles = 8;  doff = 458752; src = w6;
    }
    const int tk = id / Ntiles, tn = id % Ntiles;
    const int k0 = tk * 32, n0 = tn * 32;
    const int c = threadIdx.x & 31, r8 = threadIdx.x >> 5;
    for (int rr = r8; rr < 32; rr += 8)
        t[rr][c] = src[(size_t)(k0 + rr) * N + n0 + c];
    __syncthreads();
    for (int rr = r8; rr < 32; rr += 8)
        wt[doff + (size_t)(n0 + rr) * K + k0 + c] = f2bf(t[c][rr]);
}

// ---------------------------------------------------------------------------
// Projection MFMA GEMM with head-major scatter epilogue.
//   wsel 0 (lk): dst[b][h][x=i][a=j][d]   wsel 1 (rk): dst[b][h][a=i][y=j][d]
//   wsel 2 (lv): dst[b][h][x=i][a=j][d]   wsel 3 (rv): dst[b][h][y=j][a=i][d]
// grid = (16, 64)
// R5 lever: all 4 waves used to re-load the identical 32KB W strip from
// L1/L2 (strip exactly fills L1 while 64KB of A-rows streams through it) ->
// ~131MB of hot-line W requests, the same pathology R4 fixed in ffn.
// Stage the strip ONCE into LDS (XOR-swizzled 16B chunks: column reads at
// 512B stride would be 16-way bank conflicts; ^(col&7) makes them 2-way =
// free). W L2 requests drop 4x; L1 freed for the A stream. Bit-identical.
// ---------------------------------------------------------------------------
__global__ __launch_bounds__(256)
void proj_mfma(const unsigned short* __restrict__ A, const unsigned short* __restrict__ WT,
               unsigned short* __restrict__ projT)
{
    __shared__ unsigned short WL[64 * 256];   // [col][k] bf16, swizzled, 32KB
    const int lane = threadIdx.x & 63, wave = threadIdx.x >> 6;
    const int wsel = blockIdx.x >> 2;
    const int col0 = (blockIdx.x & 3) * 64;
    const int m0 = blockIdx.y * 128 + wave * 32;
    const int lm = lane & 15, lk8 = (lane >> 4) * 8;
    const unsigned short* W = WT + (size_t)wsel * 65536 + (size_t)col0 * 256;
    unsigned short* dst = projT + (size_t)wsel * 2097152;

    {   // stage W strip: 2048 16B chunks, 8 per thread, coalesced reads
        const int tid = threadIdx.x;
        #pragma unroll
        for (int it = 0; it < 8; ++it) {
            const int c = tid + it * 256;          // chunk id
            const int col = c >> 5, ch = c & 31;   // col 0..63, chunk-in-row 0..31
            const uint4 v = *(const uint4*)(W + (size_t)col * 256 + ch * 8);
            *(uint4*)((char*)WL + col * 512 + ((ch ^ (col & 7)) << 4)) = v;
        }
    }
    __syncthreads();

    f4 acc[2][4];
    #pragma unroll
    for (int i = 0; i < 2; ++i)
        #pragma unroll
        for (int j = 0; j < 4; ++j) acc[i][j] = (f4){0.f, 0.f, 0.f, 0.f};

    #pragma unroll 2
    for (int kc = 0; kc < 256; kc += 32) {
        short8 af[2], bf[4];
        #pragma unroll
        for (int i = 0; i < 2; ++i)
            af[i] = *(const short8*)(A + (size_t)(m0 + i * 16 + lm) * 256 + kc + lk8);
        #pragma unroll
        for (int j = 0; j < 4; ++j) {
            const int cl = j * 16 + lm;
            const int kch = (kc + lk8) >> 3;
            bf[j] = *(const short8*)((char*)WL + cl * 512 + ((kch ^ (cl & 7)) << 4));
        }
        #pragma unroll
        for (int i = 0; i < 2; ++i)
            #pragma unroll
            for (int j = 0; j < 4; ++j)
                acc[i][j] = __builtin_amdgcn_mfma_f32_16x16x32_bf16(af[i], bf[j], acc[i][j], 0, 0, 0);
    }

    const int rbase = (lane >> 4) * 4;
    const int swap = (wsel == 3);
    #pragma unroll
    for (int i = 0; i < 2; ++i)
        #pragma unroll
        for (int j = 0; j < 4; ++j) {
            const int c = col0 + j * 16 + lm;
            const int h = c >> 5, d = c & 31;
            #pragma unroll
            for (int r = 0; r < 4; ++r) {
                const int m = m0 + i * 16 + rbase + r;
                const int b = m >> 12, ii = (m >> 6) & 63, jj = m & 63;
                const int p = swap ? jj : ii;
                const int q = swap ? ii : jj;
                const size_t idx = ((((size_t)b * 8 + h) * 64 + p) * 64 + q) * 32 + d;
                dst[idx] = f2bf(acc[i][j][r]);
            }
        }
}

// ---------------------------------------------------------------------------
// Scores via MFMA: per (b,h), wave w handles a = a0 + w.
//   S_a[x,y] = sum_d lk[x,a,d]*rk[a,y,d] / sqrt(32), stored bf16 as
//   S[b][h][x][a][y].  grid = 256 (b,h,a/4), 256 thr.
// ---------------------------------------------------------------------------
__global__ __launch_bounds__(256)
void scores_mfma(const unsigned short* __restrict__ lkT, const unsigned short* __restrict__ rkT,
                 unsigned short* __restrict__ S)
{
    const int lane = threadIdx.x & 63, wave = threadIdx.x >> 6;
    const int bi = blockIdx.x;
    const int b = bi >> 7, h = (bi >> 4) & 7, a = (bi & 15) * 4 + wave;
    const size_t bh = (size_t)b * 8 + h;
    const int lm = lane & 15, lk8 = (lane >> 4) * 8;

    short8 af[4], bf[4];
    #pragma unroll
    for (int t = 0; t < 4; ++t) {
        af[t] = *(const short8*)(lkT + ((bh * 64 + (t * 16 + lm)) * 64 + a) * 32 + lk8);
        bf[t] = *(const short8*)(rkT + ((bh * 64 + a) * 64 + (t * 16 + lm)) * 32 + lk8);
    }
    const int rbase = (lane >> 4) * 4;
    unsigned short* Sb = S + bh * 262144 + a * 64;   // + x*4096 + y
    #pragma unroll
    for (int mt = 0; mt < 4; ++mt)
        #pragma unroll
        for (int nt = 0; nt < 4; ++nt) {
            f4 acc = (f4){0.f, 0.f, 0.f, 0.f};
            acc = __builtin_amdgcn_mfma_f32_16x16x32_bf16(af[mt], bf[nt], acc, 0, 0, 0);
            #pragma unroll
            for (int r = 0; r < 4; ++r) {
                const int xx = mt * 16 + rbase + r;
                const int yy = nt * 16 + lm;
                Sb[(size_t)xx * 4096 + yy] = f2bf(acc[r] * 0.17677669529663687f);
            }
        }
}

// ---------------------------------------------------------------------------
// Softmax over a + aggregation, block per (b,h,x), 256 thr.  (R4 version —
// R5's 4-x-per-block variant was reverted: rv panels are L2-set-distributed,
// not hot-line limited, so the traffic cut bought nothing and the occupancy
// drop cost ~3.6us.)
// obuf[(b*64+x)*64+y][h*32+d] bf16.  grid = 1024.
// ---------------------------------------------------------------------------
__global__ __launch_bounds__(256)
void softmax_agg(const unsigned short* __restrict__ S, const unsigned short* __restrict__ lvT,
                 const unsigned short* __restrict__ rvT, unsigned short* __restrict__ obuf)
{
    __shared__ float att[64][64];           // [a][y]
    __shared__ float lvL[64][32];
    __shared__ float smx[4][64], ssm[4][64], invL[64];
    const int bi = blockIdx.x;
    const int b = bi >> 9, h = (bi >> 6) & 7, x = bi & 63;
    const size_t bh = (size_t)b * 8 + h;
    const int tid = threadIdx.x;

    {   // load S[x] slice (8KB bf16, contiguous) -> att f32 ; stage lv -> f32
        const int a = tid >> 2, yo = (tid & 3) * 16;
        const unsigned short* Sp = S + (bh * 64 + x) * 4096 + a * 64 + yo;
        uint4 p0 = *(const uint4*)(Sp);
        uint4 p1 = *(const uint4*)(Sp + 8);
        att[a][yo +  0] = bf2f(p0.x); att[a][yo +  1] = bf2f(p0.x >> 16);
        att[a][yo +  2] = bf2f(p0.y); att[a][yo +  3] = bf2f(p0.y >> 16);
        att[a][yo +  4] = bf2f(p0.z); att[a][yo +  5] = bf2f(p0.z >> 16);
        att[a][yo +  6] = bf2f(p0.w); att[a][yo +  7] = bf2f(p0.w >> 16);
        att[a][yo +  8] = bf2f(p1.x); att[a][yo +  9] = bf2f(p1.x >> 16);
        att[a][yo + 10] = bf2f(p1.y); att[a][yo + 11] = bf2f(p1.y >> 16);
        att[a][yo + 12] = bf2f(p1.z); att[a][yo + 13] = bf2f(p1.z >> 16);
        att[a][yo + 14] = bf2f(p1.w); att[a][yo + 15] = bf2f(p1.w >> 16);
        const int d0 = (tid & 3) * 8;
        uint4 q = *(const uint4*)(lvT + ((bh * 64 + x) * 64 + a) * 32 + d0);
        lvL[a][d0 + 0] = bf2f(q.x); lvL[a][d0 + 1] = bf2f(q.x >> 16);
        lvL[a][d0 + 2] = bf2f(q.y); lvL[a][d0 + 3] = bf2f(q.y >> 16);
        lvL[a][d0 + 4] = bf2f(q.z); lvL[a][d0 + 5] = bf2f(q.z >> 16);
        lvL[a][d0 + 6] = bf2f(q.w); lvL[a][d0 + 7] = bf2f(q.w >> 16);
    }
    __syncthreads();

    {   // per-slice max over a
        const int y = tid & 63, az = tid >> 6;
        float mx = -1e30f;
        for (int a = az; a < 64; a += 4) mx = fmaxf(mx, att[a][y]);
        smx[az][y] = mx;
    }
    __syncthreads();

    {   // exp + partial sums
        const int y = tid & 63, az = tid >> 6;
        const float mx = fmaxf(fmaxf(smx[0][y], smx[1][y]), fmaxf(smx[2][y], smx[3][y]));
        float s = 0.f;
        for (int a = az; a < 64; a += 4) {
            float e = __expf(att[a][y] - mx);
            att[a][y] = e;
            s += e;
        }
        ssm[az][y] = s;
    }
    __syncthreads();
    if (tid < 64)
        invL[tid] = 1.f / (ssm[0][tid] + ssm[1][tid] + ssm[2][tid] + ssm[3][tid]);
    __syncthreads();

    {   // aggregation; thread = (dp = d-pair, yb); y = yb + 16*it
        const int dp = tid & 15, yb = tid >> 4;
        #pragma unroll
        for (int it = 0; it < 4; ++it) {
            const int y = yb + it * 16;
            const unsigned short* rvr = rvT + (bh * 64 + y) * 2048 + dp * 2;
            float a0 = 0.f, a1 = 0.f;
            #pragma unroll 8
            for (int a = 0; a < 64; ++a) {
                unsigned int pk = *(const unsigned int*)(rvr + a * 32);
                float w = att[a][y];
                a0 = fmaf(w * lvL[a][2 * dp],     bf2f(pk),       a0);
                a1 = fmaf(w * lvL[a][2 * dp + 1], bf2f(pk >> 16), a1);
            }
            const float inv = invL[y];
            a0 *= inv; a1 *= inv;
            unsigned int st = f2bf(a0) | ((unsigned int)f2bf(a1) << 16);
            *(unsigned int*)(obuf + (((size_t)b * 64 + x) * 64 + y) * 256 + h * 32 + dp * 2) = st;
        }
    }
}

// ---------------------------------------------------------------------------
// XOR swizzle on 16B chunks: row stride of both LDS tiles is a multiple of
// 128B, so unswizzled column reads (16 lanes, same col, rows 0..15) would be
// a 16-way bank conflict. chunk' = chunk ^ (row & 7) spreads them over 8
// chunk slots (2-way = free, m136).
// ---------------------------------------------------------------------------
__device__ __forceinline__ int swz8(int r, int c, int rl) {
    return r * rl + ((((c >> 3) ^ (r & 7)) << 3) | (c & 7));
}

// ---------------------------------------------------------------------------
// Fused FFN tail: one block per 32 output rows, 512 thr / 8 waves (grid 256).
//   phase 1: h   = LN(x + obuf @ WoT^T)   wave w: cols w*32..+31, rows 0..31
//   phase 2: mid = relu(h @ W1T^T + b1)   wave w: cols w*64..+63, rows 0..31
//   phase 3: out = LN(h + mid @ W2T^T+b2) wave w: cols w*32..+31, rows 0..31
// R2/R3 post-mortem: ILP (VGPR cap lift) and TLP (2x waves) both no-ops ->
// bottleneck is per-CU line-transaction / hot-line L2 throughput on the
// weight stream (every block re-reads all 640KB of weights). BM 16->32
// halves total weight traffic (320->160MB) and per-CU transactions.
// ---------------------------------------------------------------------------
__global__ __launch_bounds__(512, 2)
void ffn_fused(const unsigned short* __restrict__ A,
               const unsigned short* __restrict__ WoT,
               const unsigned short* __restrict__ W1T,
               const unsigned short* __restrict__ W2T,
               const float* __restrict__ xres,
               const float* __restrict__ g1, const float* __restrict__ be1,
               const float* __restrict__ b1, const float* __restrict__ b2,
               const float* __restrict__ g2, const float* __restrict__ be2,
               float* __restrict__ out)
{
    __shared__ unsigned short hs[32 * 256];   // h   32x256 bf16, swizzled (16KB)
    __shared__ unsigned short ms[32 * 512];   // mid 32x512 bf16, swizzled (32KB)
    __shared__ float ps[32][8], pq[32][8];
    const int lane = threadIdx.x & 63, wave = threadIdx.x >> 6;
    const int m0 = blockIdx.x * 32;
    const int lm = lane & 15, lk8 = (lane >> 4) * 8;
    const int rbase = (lane >> 4) * 4;
    const int col0 = wave * 32;               // phases 1/3: 32 cols per wave
    float hreg[2][2][4];                      // [row-tile][col-tile][r]

    // ---------- phase 1: h = LN(x + A @ WoT^T) ----------
    {
        f4 acc[2][2];
        #pragma unroll
        for (int i = 0; i < 2; ++i)
            #pragma unroll
            for (int j = 0; j < 2; ++j) acc[i][j] = (f4){0.f, 0.f, 0.f, 0.f};
        #pragma unroll
        for (int kc = 0; kc < 256; kc += 32) {
            short8 af[2], bf[2];
            #pragma unroll
            for (int i = 0; i < 2; ++i)
                af[i] = *(const short8*)(A + (size_t)(m0 + i * 16 + lm) * 256 + kc + lk8);
            #pragma unroll
            for (int j = 0; j < 2; ++j)
                bf[j] = *(const short8*)(WoT + (size_t)(col0 + j * 16 + lm) * 256 + kc + lk8);
            #pragma unroll
            for (int i = 0; i < 2; ++i)
                #pragma unroll
                for (int j = 0; j < 2; ++j)
                    acc[i][j] = __builtin_amdgcn_mfma_f32_16x16x32_bf16(af[i], bf[j], acc[i][j], 0, 0, 0);
        }
        float v[2][2][4], s[2][4], q[2][4];
        #pragma unroll
        for (int i = 0; i < 2; ++i)
            #pragma unroll
            for (int r = 0; r < 4; ++r) { s[i][r] = 0.f; q[i][r] = 0.f; }
        #pragma unroll
        for (int i = 0; i < 2; ++i)
            #pragma unroll
            for (int j = 0; j < 2; ++j) {
                const int n = col0 + j * 16 + lm;
                #pragma unroll
                for (int r = 0; r < 4; ++r) {
                    const float t = acc[i][j][r] + xres[(size_t)(m0 + i * 16 + rbase + r) * 256 + n];
                    v[i][j][r] = t;
                    s[i][r] += t;
                    q[i][r] = fmaf(t, t, q[i][r]);
                }
            }
        #pragma unroll
        for (int off = 1; off < 16; off <<= 1)
            #pragma unroll
            for (int i = 0; i < 2; ++i)
                #pragma unroll
                for (int r = 0; r < 4; ++r) {
                    s[i][r] += __shfl_xor(s[i][r], off);
                    q[i][r] += __shfl_xor(q[i][r], off);
                }
        if (lm == 0)
            #pragma unroll
            for (int i = 0; i < 2; ++i)
                #pragma unroll
                for (int r = 0; r < 4; ++r) {
                    ps[i * 16 + rbase + r][wave] = s[i][r];
                    pq[i * 16 + rbase + r][wave] = q[i][r];
                }
        __syncthreads();
        #pragma unroll
        for (int i = 0; i < 2; ++i)
            #pragma unroll
            for (int r = 0; r < 4; ++r) {
                const int lr = i * 16 + rbase + r;
                const float Sm = ps[lr][0] + ps[lr][1] + ps[lr][2] + ps[lr][3]
                               + ps[lr][4] + ps[lr][5] + ps[lr][6] + ps[lr][7];
                const float Qm = pq[lr][0] + pq[lr][1] + pq[lr][2] + pq[lr][3]
                               + pq[lr][4] + pq[lr][5] + pq[lr][6] + pq[lr][7];
                const float mu = Sm * (1.f / 256.f);
                const float ri = rsqrtf(Qm * (1.f / 256.f) - mu * mu + 1e-5f);
                #pragma unroll
                for (int j = 0; j < 2; ++j) {
                    const int n = col0 + j * 16 + lm;
                    const unsigned short hb16 = f2bf((v[i][j][r] - mu) * ri * g1[n] + be1[n]);
                    hs[swz8(lr, n, 256)] = hb16;
                    hreg[i][j][r] = bf2f(hb16);
                }
            }
    }
    __syncthreads();

    // ---------- phase 2: mid = relu(h @ W1T^T + b1) ----------
    {
        const int c0 = wave * 64;
        f4 acc2[2][4];
        #pragma unroll
        for (int i = 0; i < 2; ++i)
            #pragma unroll
            for (int j = 0; j < 4; ++j) acc2[i][j] = (f4){0.f, 0.f, 0.f, 0.f};
        #pragma unroll
        for (int kc = 0; kc < 256; kc += 32) {
            short8 af[2], bf[4];
            #pragma unroll
            for (int i = 0; i < 2; ++i)
                af[i] = *(const short8*)(hs + swz8(i * 16 + lm, kc + lk8, 256));
            #pragma unroll
            for (int j = 0; j < 4; ++j)
                bf[j] = *(const short8*)(W1T + (size_t)(c0 + j * 16 + lm) * 256 + kc + lk8);
            #pragma unroll
            for (int i = 0; i < 2; ++i)
                #pragma unroll
                for (int j = 0; j < 4; ++j)
                    acc2[i][j] = __builtin_amdgcn_mfma_f32_16x16x32_bf16(af[i], bf[j], acc2[i][j], 0, 0, 0);
        }
        #pragma unroll
        for (int i = 0; i < 2; ++i)
            #pragma unroll
            for (int j = 0; j < 4; ++j) {
                const int n = c0 + j * 16 + lm;
                const float bb = b1[n];
                #pragma unroll
                for (int r = 0; r < 4; ++r)
                    ms[swz8(i * 16 + rbase + r, n, 512)] = f2bf(fmaxf(acc2[i][j][r] + bb, 0.f));
            }
    }
    __syncthreads();

    // ---------- phase 3: out = LN(h + mid @ W2T^T + b2) ----------
    {
        f4 acc[2][2];
        #pragma unroll
        for (int i = 0; i < 2; ++i)
            #pragma unroll
            for (int j = 0; j < 2; ++j) acc[i][j] = (f4){0.f, 0.f, 0.f, 0.f};
        #pragma unroll
        for (int kc = 0; kc < 512; kc += 32) {
            short8 af[2], bf[2];
            #pragma unroll
            for (int i = 0; i < 2; ++i)
                af[i] = *(const short8*)(ms + swz8(i * 16 + lm, kc + lk8, 512));
            #pragma unroll
            for (int j = 0; j < 2; ++j)
                bf[j] = *(const short8*)(W2T + (size_t)(col0 + j * 16 + lm) * 512 + kc + lk8);
            #pragma unroll
            for (int i = 0; i < 2; ++i)
                #pragma unroll
                for (int j = 0; j < 2; ++j)
                    acc[i][j] = __builtin_amdgcn_mfma_f32_16x16x32_bf16(af[i], bf[j], acc[i][j], 0, 0, 0);
        }
        float v[2][2][4], s[2][4], q[2][4];
        #pragma unroll
        for (int i = 0; i < 2; ++i)
            #pragma unroll
            for (int r = 0; r < 4; ++r) { s[i][r] = 0.f; q[i][r] = 0.f; }
        #pragma unroll
        for (int i = 0; i < 2; ++i)
            #pragma unroll
            for (int j = 0; j < 2; ++j) {
                const int n = col0 + j * 16 + lm;
                const float bb = b2[n];
                #pragma unroll
                for (int r = 0; r < 4; ++r) {
                    const float t = acc[i][j][r] + bb + hreg[i][j][r];
                    v[i][j][r] = t;
                    s[i][r] += t;
                    q[i][r] = fmaf(t, t, q[i][r]);
                }
            }
        #pragma unroll
        for (int off = 1; off < 16; off <<= 1)
            #pragma unroll
            for (int i = 0; i < 2; ++i)
                #pragma unroll
                for (int r = 0; r < 4; ++r) {
                    s[i][r] += __shfl_xor(s[i][r], off);
                    q[i][r] += __shfl_xor(q[i][r], off);
                }
        if (lm == 0)
            #pragma unroll
            for (int i = 0; i < 2; ++i)
                #pragma unroll
                for (int r = 0; r < 4; ++r) {
                    ps[i * 16 + rbase + r][wave] = s[i][r];
                    pq[i * 16 + rbase + r][wave] = q[i][r];
                }
        __syncthreads();
        #pragma unroll
        for (int i = 0; i < 2; ++i)
            #pragma unroll
            for (int r = 0; r < 4; ++r) {
                const int lr = i * 16 + rbase + r;
                const float Sm = ps[lr][0] + ps[lr][1] + ps[lr][2] + ps[lr][3]
                               + ps[lr][4] + ps[lr][5] + ps[lr][6] + ps[lr][7];
                const float Qm = pq[lr][0] + pq[lr][1] + pq[lr][2] + pq[lr][3]
                               + pq[lr][4] + pq[lr][5] + pq[lr][6] + pq[lr][7];
                const float mu = Sm * (1.f / 256.f);
                const float ri = rsqrtf(Qm * (1.f / 256.f) - mu * mu + 1e-5f);
                const int m = m0 + lr;
                #pragma unroll
                for (int j = 0; j < 2; ++j) {
                    const int n = col0 + j * 16 + lm;
                    out[(size_t)m * 256 + n] = (v[i][j][r] - mu) * ri * g2[n] + be2[n];
                }
            }
    }
}

// ---------------------------------------------------------------------------
extern "C" void kernel_launch(void* const* d_in, const int* in_sizes, int n_in,
                              void* d_out, int out_size, void* d_ws, size_t ws_size,
                              hipStream_t stream)
{
    const float* x    = (const float*)d_in[0];
    const float* Wlk  = (const float*)d_in[1];
    const float* Wrk  = (const float*)d_in[2];
    const float* Wlv  = (const float*)d_in[3];
    const float* Wrv  = (const float*)d_in[4];
    const float* Wout = (const float*)d_in[5];
    const float* g1   = (const float*)d_in[6];
    const float* be1  = (const float*)d_in[7];
    const float* W1   = (const float*)d_in[8];
    const float* b1   = (const float*)d_in[9];
    const float* W2   = (const float*)d_in[10];
    const float* b2   = (const float*)d_in[11];
    const float* g2   = (const float*)d_in[12];
    const float* be2  = (const float*)d_in[13];

    char* base = (char*)d_ws;
    const size_t MB = 1ull << 20;
    unsigned short* xb    = (unsigned short*)(base + 0);        // 4MB; reused as obuf
    unsigned short* obufb = (unsigned short*)(base + 0);
    unsigned short* projT = (unsigned short*)(base + 4 * MB);   // lkT,rkT,lvT,rvT 4x4MB
    unsigned short* lkT   = projT;
    unsigned short* rkT   = projT + 2097152;
    unsigned short* lvT   = projT + 2 * 2097152;
    unsigned short* rvT   = projT + 3 * 2097152;
    unsigned short* Sbuf  = (unsigned short*)(base + 32 * MB);  // 8MB bf16 scores
    unsigned short* WT    = (unsigned short*)(base + 40 * MB);  // 1.2MB

    // 1. casts (x -> bf16, weights -> transposed bf16)
    cast_all<<<2624, 256, 0, stream>>>(x, xb, Wlk, Wrk, Wlv, Wrv, Wout, W1, W2, WT);
    // 2. projections + head-major scatter (W strip LDS-staged)
    proj_mfma<<<dim3(16, 64), 256, 0, stream>>>(xb, WT, projT);
    // 3. scores via MFMA -> S (bf16)
    scores_mfma<<<256, 256, 0, stream>>>(lkT, rkT, Sbuf);
    // 4. softmax + aggregation -> obuf (bf16)
    softmax_agg<<<1024, 256, 0, stream>>>(Sbuf, lvT, rvT, obufb);
    // 5-7 fused: out = LN( h + relu(h@W1+b1)@W2 + b2 ),  h = LN(x + obuf@W_out)
    ffn_fused<<<256, 512, 0, stream>>>(obufb, WT + 262144, WT + 327680, WT + 458752,
                                       x, g1, be1, b1, b2, g2, be2, (float*)d_out);
}